// Round 1
// baseline (1908.055 us; speedup 1.0000x reference)
//
#include <hip/hip_runtime.h>

#define LAYERS 6
#define DIM    768
#define D3     2304
#define DF     3072
#define TT     2048
#define VOCAB  32000

typedef unsigned short u16;
typedef __attribute__((ext_vector_type(4))) float f32x4;
typedef __attribute__((ext_vector_type(8))) short s16x8;
typedef __attribute__((ext_vector_type(4))) unsigned short u16x4;

__device__ __forceinline__ float bf2f(u16 a){
  unsigned int u = ((unsigned int)a) << 16;
  float f; __builtin_memcpy(&f, &u, 4); return f;
}
__device__ __forceinline__ u16 f2bf(float f){
  unsigned int u; __builtin_memcpy(&u, &f, 4);
  u = (u + 0x7fffu + ((u >> 16) & 1u)) >> 16;
  return (u16)u;
}
__device__ __forceinline__ void gload_lds16(const void* g, void* l){
  __builtin_amdgcn_global_load_lds(
      (const __attribute__((address_space(1))) unsigned int*)g,
      (__attribute__((address_space(3))) unsigned int*)l, 16, 0, 0);
}
__device__ __forceinline__ void mfma16(f32x4& d, s16x8 a, s16x8 b){
  asm("v_mfma_f32_16x16x32_bf16 %0, %1, %2, %0" : "+v"(d) : "v"(a), "v"(b));
}

// ---------- weight fp32 [R][C] -> bf16 [C][R] (B^T layout), grid.z = layer ----------
__global__ __launch_bounds__(256) void k_transpose(const float* __restrict__ in,
                                                   u16* __restrict__ out, int R, int C){
  __shared__ float tile[32][33];
  size_t ls = (size_t)R * C;
  in  += ls * blockIdx.z;
  out += ls * blockIdx.z;
  int r0 = blockIdx.y * 32, c0 = blockIdx.x * 32;
  int t = threadIdx.x;
  int tr = t >> 3, tc = (t & 7) * 4;
  float4 v = *(const float4*)(in + (size_t)(r0 + tr) * C + c0 + tc);
  tile[tr][tc+0] = v.x; tile[tr][tc+1] = v.y; tile[tr][tc+2] = v.z; tile[tr][tc+3] = v.w;
  __syncthreads();
  u16x4 o;
  o[0] = f2bf(tile[tc+0][tr]); o[1] = f2bf(tile[tc+1][tr]);
  o[2] = f2bf(tile[tc+2][tr]); o[3] = f2bf(tile[tc+3][tr]);
  *(u16x4*)(out + (size_t)(c0 + tr) * R + r0 + tc) = o;
}

// ---------- fp32 -> bf16 elementwise (tok_emb for tied lm_head) ----------
__global__ __launch_bounds__(256) void k_convert(const float* __restrict__ in, u16* __restrict__ out){
  int i = blockIdx.x * 256 + threadIdx.x;
  float4 v = ((const float4*)in)[i];
  u16x4 o;
  o[0] = f2bf(v.x); o[1] = f2bf(v.y); o[2] = f2bf(v.z); o[3] = f2bf(v.w);
  ((u16x4*)out)[i] = o;
}

// ---------- token + positional embedding -> x fp32 ----------
__global__ __launch_bounds__(256) void k_embed(const int* __restrict__ idx, const float* __restrict__ te,
                                               const float* __restrict__ pe, float* __restrict__ x){
  int t = blockIdx.x;
  int id = idx[t];
  const float* a = te + (size_t)id * DIM;
  const float* p = pe + (size_t)(t & 1023) * DIM;
  float* o = x + (size_t)t * DIM;
  #pragma unroll
  for (int j = 0; j < 3; ++j){
    int d = j * 256 + threadIdx.x;
    o[d] = a[d] + p[d];
  }
}

// ---------- layernorm fp32 -> bf16, one wave per row ----------
__global__ __launch_bounds__(256) void k_ln(const float* __restrict__ x, const float* __restrict__ g,
                                            const float* __restrict__ bb, u16* __restrict__ out){
  int row = blockIdx.x * 4 + (threadIdx.x >> 6);
  int lane = threadIdx.x & 63;
  const float* xr = x + (size_t)row * DIM;
  float v[12], s = 0.f;
  #pragma unroll
  for (int j = 0; j < 12; ++j){ v[j] = xr[j*64 + lane]; s += v[j]; }
  #pragma unroll
  for (int o = 32; o; o >>= 1) s += __shfl_xor(s, o);
  float mu = s * (1.f/768.f);
  float vs = 0.f;
  #pragma unroll
  for (int j = 0; j < 12; ++j){ float d = v[j]-mu; vs += d*d; }
  #pragma unroll
  for (int o = 32; o; o >>= 1) vs += __shfl_xor(vs, o);
  float rs = rsqrtf(vs * (1.f/768.f) + 1e-5f);
  u16* orow = out + (size_t)row * DIM;
  #pragma unroll
  for (int j = 0; j < 12; ++j){
    int c = j*64 + lane;
    orow[c] = f2bf((v[j]-mu)*rs*g[c] + bb[c]);
  }
}

// ---------- GEMM: A[M][K] bf16 row-major, BT[N][K] bf16, 128x128 tile, BK=32 ----------
// EPI: 0 = fp32 store (no bias); 1 = +bias -> bf16; 2 = +bias, gelu -> bf16; 3 = +bias, += fp32 resid
template<int EPI>
__global__ __launch_bounds__(256) void k_gemm(const u16* __restrict__ A, const u16* __restrict__ BT,
                                              const float* __restrict__ bias, void* __restrict__ outp,
                                              int M, int N, int K){
  __shared__ __align__(16) u16 Ab[2][4][128][8];
  __shared__ __align__(16) u16 Bb[2][4][128][8];
  int t = threadIdx.x, w = t >> 6, l = t & 63;
  int m0 = blockIdx.y * 128, n0 = blockIdx.x * 128;
  const u16* Ag = A  + (size_t)m0 * K;
  const u16* Bg = BT + (size_t)n0 * K;
  f32x4 acc[4][4] = {};
  int NT = K >> 5;

  auto stage = [&](int buf, int kt){
    int k0 = kt * 32 + w * 8;   // wave w owns k-chunk w (8 bf16 = 16B per lane)
    #pragma unroll
    for (int i = 0; i < 2; ++i){
      int row = i * 64 + l;
      gload_lds16(Ag + (size_t)row * K + k0, &Ab[buf][w][i*64][0]);
      gload_lds16(Bg + (size_t)row * K + k0, &Bb[buf][w][i*64][0]);
    }
  };

  stage(0, 0);
  __syncthreads();
  int wm = (w >> 1) * 64, wn = (w & 1) * 64;
  int ku = l >> 4, r16 = l & 15;
  for (int kt = 0; kt < NT; ++kt){
    int buf = kt & 1;
    if (kt + 1 < NT) stage(buf ^ 1, kt + 1);
    s16x8 af[4], bfr[4];
    #pragma unroll
    for (int mi = 0; mi < 4; ++mi) af[mi]  = *(const s16x8*)&Ab[buf][ku][wm + mi*16 + r16][0];
    #pragma unroll
    for (int ni = 0; ni < 4; ++ni) bfr[ni] = *(const s16x8*)&Bb[buf][ku][wn + ni*16 + r16][0];
    #pragma unroll
    for (int mi = 0; mi < 4; ++mi)
      #pragma unroll
      for (int ni = 0; ni < 4; ++ni)
        mfma16(acc[mi][ni], af[mi], bfr[ni]);
    __syncthreads();
  }
  asm volatile("s_nop 7\ns_nop 7\ns_nop 7\ns_nop 7");   // MFMA -> VALU hazard
  int rg = l >> 4;
  #pragma unroll
  for (int mi = 0; mi < 4; ++mi){
    #pragma unroll
    for (int ni = 0; ni < 4; ++ni){
      int col = n0 + wn + ni*16 + r16;
      float bv = (EPI != 0) ? bias[col] : 0.f;
      #pragma unroll
      for (int r = 0; r < 4; ++r){
        int row = m0 + wm + mi*16 + rg*4 + r;
        float v = acc[mi][ni][r] + bv;
        size_t oi = (size_t)row * N + col;
        if (EPI == 0)      ((float*)outp)[oi] = v;
        else if (EPI == 1) ((u16*)outp)[oi] = f2bf(v);
        else if (EPI == 2){ v = 0.5f*v*(1.f + erff(v*0.70710678118f)); ((u16*)outp)[oi] = f2bf(v); }
        else { float* p = (float*)outp + oi; *p += v; }
      }
    }
  }
}

// ---------- V transpose: qkv V-slice -> VT[b][h][64 d][1024 s] bf16 ----------
__global__ __launch_bounds__(256) void k_vt(const u16* __restrict__ qkv, u16* __restrict__ vt){
  int st = blockIdx.x * 64, h = blockIdx.y, b = blockIdx.z;
  __shared__ u16 tile[64][72];
  int t = threadIdx.x;
  int r = t >> 2, cg = (t & 3) * 16;
  const u16* src = qkv + (size_t)(b*1024 + st + r) * D3 + 2*DIM + h*64 + cg;
  *(s16x8*)&tile[r][cg]   = *(const s16x8*)src;
  *(s16x8*)&tile[r][cg+8] = *(const s16x8*)(src + 8);
  __syncthreads();
  s16x8 o0, o1;
  #pragma unroll
  for (int j = 0; j < 8; ++j){ o0[j] = (short)tile[cg+j][r]; o1[j] = (short)tile[cg+8+j][r]; }
  u16* dst = vt + ((size_t)(b*12 + h)*64 + r)*1024 + st + cg;
  *(s16x8*)dst     = o0;
  *(s16x8*)(dst+8) = o1;
}

// ---------- flash attention, MFMA 16x16x32; block = 64 q rows (4 waves x 16) ----------
__global__ __launch_bounds__(256) void k_attn(const u16* __restrict__ qkv, const u16* __restrict__ vt,
                                              u16* __restrict__ y){
  int qb = blockIdx.x, h = blockIdx.y, b = blockIdx.z;
  int t = threadIdx.x, wv = t >> 6, l = t & 63;
  int q0 = qb * 64;
  __shared__ __align__(16) u16 Kt[64][72];   // [k][d], +8 pad breaks bank conflicts
  __shared__ __align__(16) u16 Vtl[64][72];  // [d][k]
  __shared__ __align__(16) u16 Pl[4][16][72];
  int colb = l & 15, rowg = (l >> 4) * 4;
  // Q fragments (registers, constant across tiles)
  const u16* qp = qkv + (size_t)(b*1024 + q0 + wv*16 + colb) * D3 + h*64 + (l>>4)*8;
  s16x8 qa0 = *(const s16x8*)qp;
  s16x8 qa1 = *(const s16x8*)(qp + 32);
  f32x4 ao[4] = {};
  float m[4]  = {-1e30f,-1e30f,-1e30f,-1e30f};
  float ls[4] = {0.f,0.f,0.f,0.f};
  const u16* kbase = qkv + (size_t)b*1024*D3 + DIM + h*64;
  const u16* vbase = vt + (size_t)(b*12 + h)*64*1024;
  int kk = t >> 2, cg = (t & 3) * 16;
  int ntiles = qb + 1;
  for (int kt = 0; kt < ntiles; ++kt){
    { // stage K tile [k][d] and V^T tile [d][k]
      const u16* ks = kbase + (size_t)(kt*64 + kk) * D3 + cg;
      *(s16x8*)&Kt[kk][cg]    = *(const s16x8*)ks;
      *(s16x8*)&Kt[kk][cg+8]  = *(const s16x8*)(ks + 8);
      const u16* vs = vbase + (size_t)kk * 1024 + kt*64 + cg;
      *(s16x8*)&Vtl[kk][cg]   = *(const s16x8*)vs;
      *(s16x8*)&Vtl[kk][cg+8] = *(const s16x8*)(vs + 8);
    }
    __syncthreads();
    // QK^T
    f32x4 as[4];
    #pragma unroll
    for (int nf = 0; nf < 4; ++nf){
      as[nf] = 0.f;
      s16x8 b0 = *(const s16x8*)&Kt[nf*16 + colb][(l>>4)*8];
      s16x8 b1 = *(const s16x8*)&Kt[nf*16 + colb][32 + (l>>4)*8];
      mfma16(as[nf], qa0, b0);
      mfma16(as[nf], qa1, b1);
    }
    asm volatile("s_nop 7\ns_nop 7\ns_nop 7");   // MFMA -> VALU hazard
    // mask + online softmax (fp32)
    float sv[4][4];
    int qgb = q0 + wv*16 + rowg;
    #pragma unroll
    for (int nf = 0; nf < 4; ++nf){
      int kglob = kt*64 + nf*16 + colb;
      #pragma unroll
      for (int r = 0; r < 4; ++r){
        float s = as[nf][r] * 0.125f;
        sv[nf][r] = (kglob > qgb + r) ? -1e30f : s;
      }
    }
    float corr[4], rs[4];
    #pragma unroll
    for (int r = 0; r < 4; ++r){
      float v = fmaxf(fmaxf(sv[0][r], sv[1][r]), fmaxf(sv[2][r], sv[3][r]));
      v = fmaxf(v, __shfl_xor(v, 1)); v = fmaxf(v, __shfl_xor(v, 2));
      v = fmaxf(v, __shfl_xor(v, 4)); v = fmaxf(v, __shfl_xor(v, 8));
      float mn = fmaxf(m[r], v);
      corr[r] = __expf(m[r] - mn);
      m[r] = mn;
      rs[r] = 0.f;
    }
    #pragma unroll
    for (int nf = 0; nf < 4; ++nf){
      #pragma unroll
      for (int r = 0; r < 4; ++r){
        float p = __expf(sv[nf][r] - m[r]);
        rs[r] += p;
        Pl[wv][rowg + r][nf*16 + colb] = f2bf(p);
      }
    }
    #pragma unroll
    for (int r = 0; r < 4; ++r){
      float v = rs[r];
      v += __shfl_xor(v, 1); v += __shfl_xor(v, 2); v += __shfl_xor(v, 4); v += __shfl_xor(v, 8);
      ls[r] = ls[r]*corr[r] + v;
    }
    #pragma unroll
    for (int nf = 0; nf < 4; ++nf)
      #pragma unroll
      for (int r = 0; r < 4; ++r)
        ao[nf][r] *= corr[r];
    asm volatile("s_waitcnt lgkmcnt(0)" ::: "memory");   // P writes -> P reads (wave-local)
    // PV
    s16x8 pa0 = *(const s16x8*)&Pl[wv][colb][(l>>4)*8];
    s16x8 pa1 = *(const s16x8*)&Pl[wv][colb][32 + (l>>4)*8];
    #pragma unroll
    for (int nf = 0; nf < 4; ++nf){
      s16x8 v0 = *(const s16x8*)&Vtl[nf*16 + colb][(l>>4)*8];
      s16x8 v1 = *(const s16x8*)&Vtl[nf*16 + colb][32 + (l>>4)*8];
      mfma16(ao[nf], pa0, v0);
      mfma16(ao[nf], pa1, v1);
    }
    __syncthreads();
  }
  asm volatile("s_nop 7\ns_nop 7\ns_nop 7\ns_nop 7");
  #pragma unroll
  for (int nf = 0; nf < 4; ++nf){
    #pragma unroll
    for (int r = 0; r < 4; ++r){
      int qg = q0 + wv*16 + rowg + r;
      int d  = nf*16 + colb;
      y[(size_t)(b*1024 + qg)*DIM + h*64 + d] = f2bf(ao[nf][r] / ls[r]);
    }
  }
}

extern "C" void kernel_launch(void* const* d_in, const int* in_sizes, int n_in,
                              void* d_out, int out_size, void* d_ws, size_t ws_size,
                              hipStream_t stream){
  (void)in_sizes; (void)n_in; (void)out_size; (void)ws_size;
  const int*   idx     = (const int*)  d_in[0];
  const float* tok_emb = (const float*)d_in[1];
  const float* pos_emb = (const float*)d_in[2];
  const float* ln1_g   = (const float*)d_in[3];
  const float* ln1_b   = (const float*)d_in[4];
  const float* qkv_w   = (const float*)d_in[5];
  const float* qkv_b   = (const float*)d_in[6];
  const float* attn_w  = (const float*)d_in[7];
  const float* attn_b  = (const float*)d_in[8];
  const float* ln2_g   = (const float*)d_in[9];
  const float* ln2_b   = (const float*)d_in[10];
  const float* fc_w    = (const float*)d_in[11];
  const float* fc_b    = (const float*)d_in[12];
  const float* mlp_w   = (const float*)d_in[13];
  const float* mlp_b   = (const float*)d_in[14];
  const float* lnf_g   = (const float*)d_in[15];
  const float* lnf_b   = (const float*)d_in[16];

  char* ws = (char*)d_ws;
  size_t off = 0;
  auto take = [&](size_t bytes)->char*{
    char* p = ws + off; off += (bytes + 255) & ~(size_t)255; return p;
  };
  u16*   wqkvT = (u16*)  take((size_t)LAYERS*D3*DIM*2);
  u16*   wattT = (u16*)  take((size_t)LAYERS*DIM*DIM*2);
  u16*   wfcT  = (u16*)  take((size_t)LAYERS*DF*DIM*2);
  u16*   wmlpT = (u16*)  take((size_t)LAYERS*DIM*DF*2);
  u16*   embB  = (u16*)  take((size_t)VOCAB*DIM*2);
  float* x     = (float*)take((size_t)TT*DIM*4);
  u16*   hbuf  = (u16*)  take((size_t)TT*DIM*2);
  u16*   qkvb  = (u16*)  take((size_t)TT*D3*2);
  u16*   yb    = (u16*)  take((size_t)TT*DIM*2);
  u16*   fcb   = (u16*)  take((size_t)TT*DF*2);
  u16*   xfb   = (u16*)  take((size_t)TT*DIM*2);
  u16*   vtb   = (u16*)  take((size_t)2*12*64*1024*2);

  // weight prep (bf16 + B^T layout)
  k_transpose<<<dim3(D3/32,  DIM/32, LAYERS), 256, 0, stream>>>(qkv_w, wqkvT, DIM, D3);
  k_transpose<<<dim3(DIM/32, DIM/32, LAYERS), 256, 0, stream>>>(attn_w, wattT, DIM, DIM);
  k_transpose<<<dim3(DF/32,  DIM/32, LAYERS), 256, 0, stream>>>(fc_w,  wfcT,  DIM, DF);
  k_transpose<<<dim3(DIM/32, DF/32,  LAYERS), 256, 0, stream>>>(mlp_w, wmlpT, DF, DIM);
  k_convert<<<(VOCAB*DIM)/1024, 256, 0, stream>>>(tok_emb, embB);

  k_embed<<<TT, 256, 0, stream>>>(idx, tok_emb, pos_emb, x);

  for (int l = 0; l < LAYERS; ++l){
    k_ln<<<TT/4, 256, 0, stream>>>(x, ln1_g + l*DIM, ln1_b + l*DIM, hbuf);
    k_gemm<1><<<dim3(D3/128, TT/128), 256, 0, stream>>>(
        hbuf, wqkvT + (size_t)l*D3*DIM, qkv_b + l*D3, qkvb, TT, D3, DIM);
    k_vt<<<dim3(16, 12, 2), 256, 0, stream>>>(qkvb, vtb);
    k_attn<<<dim3(16, 12, 2), 256, 0, stream>>>(qkvb, vtb, yb);
    k_gemm<3><<<dim3(DIM/128, TT/128), 256, 0, stream>>>(
        yb, wattT + (size_t)l*DIM*DIM, attn_b + l*DIM, x, TT, DIM, DIM);
    k_ln<<<TT/4, 256, 0, stream>>>(x, ln2_g + l*DIM, ln2_b + l*DIM, hbuf);
    k_gemm<2><<<dim3(DF/128, TT/128), 256, 0, stream>>>(
        hbuf, wfcT + (size_t)l*DF*DIM, fc_b + l*DF, fcb, TT, DF, DIM);
    k_gemm<3><<<dim3(DIM/128, TT/128), 256, 0, stream>>>(
        fcb, wmlpT + (size_t)l*DIM*DF, mlp_b + l*DIM, x, TT, DIM, DF);
  }
  k_ln<<<TT/4, 256, 0, stream>>>(x, lnf_g, lnf_b, xfb);
  k_gemm<0><<<dim3(VOCAB/128, TT/128), 256, 0, stream>>>(
      xfb, embB, nullptr, d_out, TT, VOCAB, DIM);
}

// Round 2
// 1578.082 us; speedup vs baseline: 1.2091x; 1.2091x over previous
//
#include <hip/hip_runtime.h>

#define LAYERS 6
#define DIM    768
#define D3     2304
#define DF     3072
#define TT     2048
#define VOCAB  32000

typedef unsigned short u16;
typedef __attribute__((ext_vector_type(4))) float f32x4;
typedef __attribute__((ext_vector_type(8))) short s16x8;
typedef __attribute__((ext_vector_type(4))) unsigned short u16x4;

__device__ __forceinline__ float bf2f(u16 a){
  unsigned int u = ((unsigned int)a) << 16;
  float f; __builtin_memcpy(&f, &u, 4); return f;
}
__device__ __forceinline__ u16 f2bf(float f){
  unsigned int u; __builtin_memcpy(&u, &f, 4);
  u = (u + 0x7fffu + ((u >> 16) & 1u)) >> 16;
  return (u16)u;
}
__device__ __forceinline__ void gload_lds16(const void* g, void* l){
  __builtin_amdgcn_global_load_lds(
      (const __attribute__((address_space(1))) unsigned int*)g,
      (__attribute__((address_space(3))) unsigned int*)l, 16, 0, 0);
}
__device__ __forceinline__ void mfma16(f32x4& d, s16x8 a, s16x8 b){
  asm("v_mfma_f32_16x16x32_bf16 %0, %1, %2, %0" : "+v"(d) : "v"(a), "v"(b));
}

// ---------- weight fp32 [R][C] -> bf16 [C][R] (B^T layout), grid.z = layer ----------
__global__ __launch_bounds__(256) void k_transpose(const float* __restrict__ in,
                                                   u16* __restrict__ out, int R, int C){
  __shared__ float tile[32][33];
  size_t ls = (size_t)R * C;
  in  += ls * blockIdx.z;
  out += ls * blockIdx.z;
  int r0 = blockIdx.y * 32, c0 = blockIdx.x * 32;
  int t = threadIdx.x;
  int tr = t >> 3, tc = (t & 7) * 4;
  float4 v = *(const float4*)(in + (size_t)(r0 + tr) * C + c0 + tc);
  tile[tr][tc+0] = v.x; tile[tr][tc+1] = v.y; tile[tr][tc+2] = v.z; tile[tr][tc+3] = v.w;
  __syncthreads();
  u16x4 o;
  o[0] = f2bf(tile[tc+0][tr]); o[1] = f2bf(tile[tc+1][tr]);
  o[2] = f2bf(tile[tc+2][tr]); o[3] = f2bf(tile[tc+3][tr]);
  *(u16x4*)(out + (size_t)(c0 + tr) * R + r0 + tc) = o;
}

// ---------- fp32 -> bf16 elementwise (tok_emb for tied lm_head) ----------
__global__ __launch_bounds__(256) void k_convert(const float* __restrict__ in, u16* __restrict__ out){
  int i = blockIdx.x * 256 + threadIdx.x;
  float4 v = ((const float4*)in)[i];
  u16x4 o;
  o[0] = f2bf(v.x); o[1] = f2bf(v.y); o[2] = f2bf(v.z); o[3] = f2bf(v.w);
  ((u16x4*)out)[i] = o;
}

// ---------- token + positional embedding -> x fp32 ----------
__global__ __launch_bounds__(256) void k_embed(const int* __restrict__ idx, const float* __restrict__ te,
                                               const float* __restrict__ pe, float* __restrict__ x){
  int t = blockIdx.x;
  int id = idx[t];
  const float* a = te + (size_t)id * DIM;
  const float* p = pe + (size_t)(t & 1023) * DIM;
  float* o = x + (size_t)t * DIM;
  #pragma unroll
  for (int j = 0; j < 3; ++j){
    int d = j * 256 + threadIdx.x;
    o[d] = a[d] + p[d];
  }
}

// ---------- layernorm fp32 -> bf16, one wave per row ----------
__global__ __launch_bounds__(256) void k_ln(const float* __restrict__ x, const float* __restrict__ g,
                                            const float* __restrict__ bb, u16* __restrict__ out){
  int row = blockIdx.x * 4 + (threadIdx.x >> 6);
  int lane = threadIdx.x & 63;
  const float* xr = x + (size_t)row * DIM;
  float v[12], s = 0.f;
  #pragma unroll
  for (int j = 0; j < 12; ++j){ v[j] = xr[j*64 + lane]; s += v[j]; }
  #pragma unroll
  for (int o = 32; o; o >>= 1) s += __shfl_xor(s, o);
  float mu = s * (1.f/768.f);
  float vs = 0.f;
  #pragma unroll
  for (int j = 0; j < 12; ++j){ float d = v[j]-mu; vs += d*d; }
  #pragma unroll
  for (int o = 32; o; o >>= 1) vs += __shfl_xor(vs, o);
  float rs = rsqrtf(vs * (1.f/768.f) + 1e-5f);
  u16* orow = out + (size_t)row * DIM;
  #pragma unroll
  for (int j = 0; j < 12; ++j){
    int c = j*64 + lane;
    orow[c] = f2bf((v[j]-mu)*rs*g[c] + bb[c]);
  }
}

// ---------- GEMM: A[M=2048][K] bf16 row-major, BT[N][K] bf16, 128x128 tile, BK=32 ----------
// 1-D grid, bijective XCD swizzle + m-fastest grouping (16 m-tiles share one B-panel per XCD).
// EPI: 0 = fp32 store (no bias); 1 = +bias -> bf16; 2 = +bias, gelu -> bf16; 3 = +bias, += fp32 resid
template<int EPI>
__global__ __launch_bounds__(256) void k_gemm(const u16* __restrict__ A, const u16* __restrict__ BT,
                                              const float* __restrict__ bias, void* __restrict__ outp,
                                              int N, int K){
  __shared__ __align__(16) u16 Ab[2][128][32];
  __shared__ __align__(16) u16 Bb[2][128][32];
  int t = threadIdx.x, w = t >> 6, l = t & 63;
  // XCD swizzle: each XCD gets a contiguous wgid chunk; within chunk m varies fastest.
  int cpx = gridDim.x >> 3;               // all grids divisible by 8
  int wgid = (blockIdx.x & 7) * cpx + (blockIdx.x >> 3);
  int m0 = (wgid & 15) * 128;             // M/128 == 16 always (M = 2048)
  int n0 = (wgid >> 4) * 128;
  const u16* Ag = A  + (size_t)m0 * K;
  const u16* Bg = BT + (size_t)n0 * K;
  f32x4 acc[4][4] = {};
  int NT = K >> 5;
  int lr = l >> 2, lc = (l & 3) * 8;      // 4 lanes cover one 64B row-chunk

  auto stage = [&](int buf, int kt){
    int k0 = kt * 32 + lc;
    int rb = w * 16;
    gload_lds16(Ag + (size_t)(rb + lr) * K + k0,      &Ab[buf][rb][0]);
    gload_lds16(Ag + (size_t)(64 + rb + lr) * K + k0, &Ab[buf][64 + rb][0]);
    gload_lds16(Bg + (size_t)(rb + lr) * K + k0,      &Bb[buf][rb][0]);
    gload_lds16(Bg + (size_t)(64 + rb + lr) * K + k0, &Bb[buf][64 + rb][0]);
  };

  stage(0, 0);
  __syncthreads();
  int wm = (w >> 1) * 64, wn = (w & 1) * 64;
  int ku = l >> 4, r16 = l & 15;
  for (int kt = 0; kt < NT; ++kt){
    int buf = kt & 1;
    if (kt + 1 < NT) stage(buf ^ 1, kt + 1);
    s16x8 af[4], bfr[4];
    #pragma unroll
    for (int mi = 0; mi < 4; ++mi) af[mi]  = *(const s16x8*)&Ab[buf][wm + mi*16 + r16][ku*8];
    #pragma unroll
    for (int ni = 0; ni < 4; ++ni) bfr[ni] = *(const s16x8*)&Bb[buf][wn + ni*16 + r16][ku*8];
    #pragma unroll
    for (int mi = 0; mi < 4; ++mi)
      #pragma unroll
      for (int ni = 0; ni < 4; ++ni)
        mfma16(acc[mi][ni], af[mi], bfr[ni]);
    __syncthreads();
  }
  asm volatile("s_nop 7\ns_nop 7\ns_nop 7\ns_nop 7");   // MFMA -> VALU hazard
  int rg = l >> 4;
  #pragma unroll
  for (int mi = 0; mi < 4; ++mi){
    #pragma unroll
    for (int ni = 0; ni < 4; ++ni){
      int col = n0 + wn + ni*16 + r16;
      float bv = (EPI != 0) ? bias[col] : 0.f;
      #pragma unroll
      for (int r = 0; r < 4; ++r){
        int row = m0 + wm + mi*16 + rg*4 + r;
        float v = acc[mi][ni][r] + bv;
        size_t oi = (size_t)row * N + col;
        if (EPI == 0)      ((float*)outp)[oi] = v;
        else if (EPI == 1) ((u16*)outp)[oi] = f2bf(v);
        else if (EPI == 2){ v = 0.5f*v*(1.f + erff(v*0.70710678118f)); ((u16*)outp)[oi] = f2bf(v); }
        else { float* p = (float*)outp + oi; *p += v; }
      }
    }
  }
}

// ---------- V transpose: qkv V-slice -> VT[b][h][64 d][1024 s] bf16 ----------
__global__ __launch_bounds__(256) void k_vt(const u16* __restrict__ qkv, u16* __restrict__ vt){
  int st = blockIdx.x * 64, h = blockIdx.y, b = blockIdx.z;
  __shared__ u16 tile[64][72];
  int t = threadIdx.x;
  int r = t >> 2, cg = (t & 3) * 16;
  const u16* src = qkv + (size_t)(b*1024 + st + r) * D3 + 2*DIM + h*64 + cg;
  *(s16x8*)&tile[r][cg]   = *(const s16x8*)src;
  *(s16x8*)&tile[r][cg+8] = *(const s16x8*)(src + 8);
  __syncthreads();
  s16x8 o0, o1;
  #pragma unroll
  for (int j = 0; j < 8; ++j){ o0[j] = (short)tile[cg+j][r]; o1[j] = (short)tile[cg+8+j][r]; }
  u16* dst = vt + ((size_t)(b*12 + h)*64 + r)*1024 + st + cg;
  *(s16x8*)dst     = o0;
  *(s16x8*)(dst+8) = o1;
}

// ---------- flash attention, MFMA 16x16x32; block = 64 q rows (4 waves x 16) ----------
__global__ __launch_bounds__(256) void k_attn(const u16* __restrict__ qkv, const u16* __restrict__ vt,
                                              u16* __restrict__ y){
  int qb = blockIdx.x, h = blockIdx.y, b = blockIdx.z;
  int t = threadIdx.x, wv = t >> 6, l = t & 63;
  int q0 = qb * 64;
  __shared__ __align__(16) u16 Kt[64][72];   // [k][d], +8 pad breaks bank conflicts
  __shared__ __align__(16) u16 Vtl[64][72];  // [d][k]
  __shared__ __align__(16) u16 Pl[4][16][72];
  int colb = l & 15, rowg = (l >> 4) * 4;
  // Q fragments (registers, constant across tiles)
  const u16* qp = qkv + (size_t)(b*1024 + q0 + wv*16 + colb) * D3 + h*64 + (l>>4)*8;
  s16x8 qa0 = *(const s16x8*)qp;
  s16x8 qa1 = *(const s16x8*)(qp + 32);
  f32x4 ao[4] = {};
  float m[4]  = {-1e30f,-1e30f,-1e30f,-1e30f};
  float ls[4] = {0.f,0.f,0.f,0.f};
  const u16* kbase = qkv + (size_t)b*1024*D3 + DIM + h*64;
  const u16* vbase = vt + (size_t)(b*12 + h)*64*1024;
  int kk = t >> 2, cg = (t & 3) * 16;
  int ntiles = qb + 1;
  for (int kt = 0; kt < ntiles; ++kt){
    { // stage K tile [k][d] and V^T tile [d][k]
      const u16* ks = kbase + (size_t)(kt*64 + kk) * D3 + cg;
      *(s16x8*)&Kt[kk][cg]    = *(const s16x8*)ks;
      *(s16x8*)&Kt[kk][cg+8]  = *(const s16x8*)(ks + 8);
      const u16* vs = vbase + (size_t)kk * 1024 + kt*64 + cg;
      *(s16x8*)&Vtl[kk][cg]   = *(const s16x8*)vs;
      *(s16x8*)&Vtl[kk][cg+8] = *(const s16x8*)(vs + 8);
    }
    __syncthreads();
    // QK^T
    f32x4 as[4];
    #pragma unroll
    for (int nf = 0; nf < 4; ++nf){
      as[nf] = 0.f;
      s16x8 b0 = *(const s16x8*)&Kt[nf*16 + colb][(l>>4)*8];
      s16x8 b1 = *(const s16x8*)&Kt[nf*16 + colb][32 + (l>>4)*8];
      mfma16(as[nf], qa0, b0);
      mfma16(as[nf], qa1, b1);
    }
    asm volatile("s_nop 7\ns_nop 7\ns_nop 7");   // MFMA -> VALU hazard
    // mask + online softmax (fp32)
    float sv[4][4];
    int qgb = q0 + wv*16 + rowg;
    #pragma unroll
    for (int nf = 0; nf < 4; ++nf){
      int kglob = kt*64 + nf*16 + colb;
      #pragma unroll
      for (int r = 0; r < 4; ++r){
        float s = as[nf][r] * 0.125f;
        sv[nf][r] = (kglob > qgb + r) ? -1e30f : s;
      }
    }
    float corr[4], rs[4];
    #pragma unroll
    for (int r = 0; r < 4; ++r){
      float v = fmaxf(fmaxf(sv[0][r], sv[1][r]), fmaxf(sv[2][r], sv[3][r]));
      v = fmaxf(v, __shfl_xor(v, 1)); v = fmaxf(v, __shfl_xor(v, 2));
      v = fmaxf(v, __shfl_xor(v, 4)); v = fmaxf(v, __shfl_xor(v, 8));
      float mn = fmaxf(m[r], v);
      corr[r] = __expf(m[r] - mn);
      m[r] = mn;
      rs[r] = 0.f;
    }
    #pragma unroll
    for (int nf = 0; nf < 4; ++nf){
      #pragma unroll
      for (int r = 0; r < 4; ++r){
        float p = __expf(sv[nf][r] - m[r]);
        rs[r] += p;
        Pl[wv][rowg + r][nf*16 + colb] = f2bf(p);
      }
    }
    #pragma unroll
    for (int r = 0; r < 4; ++r){
      float v = rs[r];
      v += __shfl_xor(v, 1); v += __shfl_xor(v, 2); v += __shfl_xor(v, 4); v += __shfl_xor(v, 8);
      ls[r] = ls[r]*corr[r] + v;
    }
    #pragma unroll
    for (int nf = 0; nf < 4; ++nf)
      #pragma unroll
      for (int r = 0; r < 4; ++r)
        ao[nf][r] *= corr[r];
    asm volatile("s_waitcnt lgkmcnt(0)" ::: "memory");   // P writes -> P reads (wave-local)
    // PV
    s16x8 pa0 = *(const s16x8*)&Pl[wv][colb][(l>>4)*8];
    s16x8 pa1 = *(const s16x8*)&Pl[wv][colb][32 + (l>>4)*8];
    #pragma unroll
    for (int nf = 0; nf < 4; ++nf){
      s16x8 v0 = *(const s16x8*)&Vtl[nf*16 + colb][(l>>4)*8];
      s16x8 v1 = *(const s16x8*)&Vtl[nf*16 + colb][32 + (l>>4)*8];
      mfma16(ao[nf], pa0, v0);
      mfma16(ao[nf], pa1, v1);
    }
    __syncthreads();
  }
  asm volatile("s_nop 7\ns_nop 7\ns_nop 7\ns_nop 7");
  #pragma unroll
  for (int nf = 0; nf < 4; ++nf){
    #pragma unroll
    for (int r = 0; r < 4; ++r){
      int qg = q0 + wv*16 + rowg + r;
      int d  = nf*16 + colb;
      y[(size_t)(b*1024 + qg)*DIM + h*64 + d] = f2bf(ao[nf][r] / ls[r]);
    }
  }
}

extern "C" void kernel_launch(void* const* d_in, const int* in_sizes, int n_in,
                              void* d_out, int out_size, void* d_ws, size_t ws_size,
                              hipStream_t stream){
  (void)in_sizes; (void)n_in; (void)out_size; (void)ws_size;
  const int*   idx     = (const int*)  d_in[0];
  const float* tok_emb = (const float*)d_in[1];
  const float* pos_emb = (const float*)d_in[2];
  const float* ln1_g   = (const float*)d_in[3];
  const float* ln1_b   = (const float*)d_in[4];
  const float* qkv_w   = (const float*)d_in[5];
  const float* qkv_b   = (const float*)d_in[6];
  const float* attn_w  = (const float*)d_in[7];
  const float* attn_b  = (const float*)d_in[8];
  const float* ln2_g   = (const float*)d_in[9];
  const float* ln2_b   = (const float*)d_in[10];
  const float* fc_w    = (const float*)d_in[11];
  const float* fc_b    = (const float*)d_in[12];
  const float* mlp_w   = (const float*)d_in[13];
  const float* mlp_b   = (const float*)d_in[14];
  const float* lnf_g   = (const float*)d_in[15];
  const float* lnf_b   = (const float*)d_in[16];

  char* ws = (char*)d_ws;
  size_t off = 0;
  auto take = [&](size_t bytes)->char*{
    char* p = ws + off; off += (bytes + 255) & ~(size_t)255; return p;
  };
  u16*   wqkvT = (u16*)  take((size_t)LAYERS*D3*DIM*2);
  u16*   wattT = (u16*)  take((size_t)LAYERS*DIM*DIM*2);
  u16*   wfcT  = (u16*)  take((size_t)LAYERS*DF*DIM*2);
  u16*   wmlpT = (u16*)  take((size_t)LAYERS*DIM*DF*2);
  u16*   embB  = (u16*)  take((size_t)VOCAB*DIM*2);
  float* x     = (float*)take((size_t)TT*DIM*4);
  u16*   hbuf  = (u16*)  take((size_t)TT*DIM*2);
  u16*   qkvb  = (u16*)  take((size_t)TT*D3*2);
  u16*   yb    = (u16*)  take((size_t)TT*DIM*2);
  u16*   fcb   = (u16*)  take((size_t)TT*DF*2);
  u16*   xfb   = (u16*)  take((size_t)TT*DIM*2);
  u16*   vtb   = (u16*)  take((size_t)2*12*64*1024*2);

  // weight prep (bf16 + B^T layout)
  k_transpose<<<dim3(D3/32,  DIM/32, LAYERS), 256, 0, stream>>>(qkv_w, wqkvT, DIM, D3);
  k_transpose<<<dim3(DIM/32, DIM/32, LAYERS), 256, 0, stream>>>(attn_w, wattT, DIM, DIM);
  k_transpose<<<dim3(DF/32,  DIM/32, LAYERS), 256, 0, stream>>>(fc_w,  wfcT,  DIM, DF);
  k_transpose<<<dim3(DIM/32, DF/32,  LAYERS), 256, 0, stream>>>(mlp_w, wmlpT, DF, DIM);
  k_convert<<<(VOCAB*DIM)/1024, 256, 0, stream>>>(tok_emb, embB);

  k_embed<<<TT, 256, 0, stream>>>(idx, tok_emb, pos_emb, x);

  for (int l = 0; l < LAYERS; ++l){
    k_ln<<<TT/4, 256, 0, stream>>>(x, ln1_g + l*DIM, ln1_b + l*DIM, hbuf);
    k_gemm<1><<<dim3((TT/128)*(D3/128)), 256, 0, stream>>>(
        hbuf, wqkvT + (size_t)l*D3*DIM, qkv_b + l*D3, qkvb, D3, DIM);
    k_vt<<<dim3(16, 12, 2), 256, 0, stream>>>(qkvb, vtb);
    k_attn<<<dim3(16, 12, 2), 256, 0, stream>>>(qkvb, vtb, yb);
    k_gemm<3><<<dim3((TT/128)*(DIM/128)), 256, 0, stream>>>(
        yb, wattT + (size_t)l*DIM*DIM, attn_b + l*DIM, x, DIM, DIM);
    k_ln<<<TT/4, 256, 0, stream>>>(x, ln2_g + l*DIM, ln2_b + l*DIM, hbuf);
    k_gemm<2><<<dim3((TT/128)*(DF/128)), 256, 0, stream>>>(
        hbuf, wfcT + (size_t)l*DF*DIM, fc_b + l*DF, fcb, DF, DIM);
    k_gemm<3><<<dim3((TT/128)*(DIM/128)), 256, 0, stream>>>(
        fcb, wmlpT + (size_t)l*DIM*DF, mlp_b + l*DIM, x, DIM, DF);
  }
  k_ln<<<TT/4, 256, 0, stream>>>(x, lnf_g, lnf_b, xfb);
  k_gemm<0><<<dim3((TT/128)*(VOCAB/128)), 256, 0, stream>>>(
      xfb, embB, nullptr, d_out, VOCAB, DIM);
}

// Round 3
// 1547.689 us; speedup vs baseline: 1.2328x; 1.0196x over previous
//
#include <hip/hip_runtime.h>

#define LAYERS 6
#define DIM    768
#define D3     2304
#define DF     3072
#define TT     2048
#define VOCAB  32000

typedef unsigned short u16;
typedef __attribute__((ext_vector_type(4))) float f32x4;
typedef __attribute__((ext_vector_type(8))) short s16x8;
typedef __attribute__((ext_vector_type(4))) unsigned short u16x4;

__device__ __forceinline__ float bf2f(u16 a){
  unsigned int u = ((unsigned int)a) << 16;
  float f; __builtin_memcpy(&f, &u, 4); return f;
}
__device__ __forceinline__ u16 f2bf(float f){
  unsigned int u; __builtin_memcpy(&u, &f, 4);
  u = (u + 0x7fffu + ((u >> 16) & 1u)) >> 16;
  return (u16)u;
}
__device__ __forceinline__ void gload_lds16(const void* g, void* l){
  __builtin_amdgcn_global_load_lds(
      (const __attribute__((address_space(1))) unsigned int*)g,
      (__attribute__((address_space(3))) unsigned int*)l, 16, 0, 0);
}
__device__ __forceinline__ void mfma16(f32x4& d, s16x8 a, s16x8 b){
  asm("v_mfma_f32_16x16x32_bf16 %0, %1, %2, %0" : "+v"(d) : "v"(a), "v"(b));
}

// ---------- weight fp32 [R][C] -> bf16 [C][R] (B^T layout), grid.z = layer ----------
__global__ __launch_bounds__(256) void k_transpose(const float* __restrict__ in,
                                                   u16* __restrict__ out, int R, int C){
  __shared__ float tile[32][33];
  size_t ls = (size_t)R * C;
  in  += ls * blockIdx.z;
  out += ls * blockIdx.z;
  int r0 = blockIdx.y * 32, c0 = blockIdx.x * 32;
  int t = threadIdx.x;
  int tr = t >> 3, tc = (t & 7) * 4;
  float4 v = *(const float4*)(in + (size_t)(r0 + tr) * C + c0 + tc);
  tile[tr][tc+0] = v.x; tile[tr][tc+1] = v.y; tile[tr][tc+2] = v.z; tile[tr][tc+3] = v.w;
  __syncthreads();
  u16x4 o;
  o[0] = f2bf(tile[tc+0][tr]); o[1] = f2bf(tile[tc+1][tr]);
  o[2] = f2bf(tile[tc+2][tr]); o[3] = f2bf(tile[tc+3][tr]);
  *(u16x4*)(out + (size_t)(c0 + tr) * R + r0 + tc) = o;
}

// ---------- fp32 -> bf16 elementwise (tok_emb for tied lm_head) ----------
__global__ __launch_bounds__(256) void k_convert(const float* __restrict__ in, u16* __restrict__ out){
  int i = blockIdx.x * 256 + threadIdx.x;
  float4 v = ((const float4*)in)[i];
  u16x4 o;
  o[0] = f2bf(v.x); o[1] = f2bf(v.y); o[2] = f2bf(v.z); o[3] = f2bf(v.w);
  ((u16x4*)out)[i] = o;
}

// ---------- token + positional embedding -> x fp32 ----------
__global__ __launch_bounds__(256) void k_embed(const int* __restrict__ idx, const float* __restrict__ te,
                                               const float* __restrict__ pe, float* __restrict__ x){
  int t = blockIdx.x;
  int id = idx[t];
  const float* a = te + (size_t)id * DIM;
  const float* p = pe + (size_t)(t & 1023) * DIM;
  float* o = x + (size_t)t * DIM;
  #pragma unroll
  for (int j = 0; j < 3; ++j){
    int d = j * 256 + threadIdx.x;
    o[d] = a[d] + p[d];
  }
}

// ---------- layernorm fp32 -> bf16, one wave per row ----------
__global__ __launch_bounds__(256) void k_ln(const float* __restrict__ x, const float* __restrict__ g,
                                            const float* __restrict__ bb, u16* __restrict__ out){
  int row = blockIdx.x * 4 + (threadIdx.x >> 6);
  int lane = threadIdx.x & 63;
  const float* xr = x + (size_t)row * DIM;
  float v[12], s = 0.f;
  #pragma unroll
  for (int j = 0; j < 12; ++j){ v[j] = xr[j*64 + lane]; s += v[j]; }
  #pragma unroll
  for (int o = 32; o; o >>= 1) s += __shfl_xor(s, o);
  float mu = s * (1.f/768.f);
  float vs = 0.f;
  #pragma unroll
  for (int j = 0; j < 12; ++j){ float d = v[j]-mu; vs += d*d; }
  #pragma unroll
  for (int o = 32; o; o >>= 1) vs += __shfl_xor(vs, o);
  float rs = rsqrtf(vs * (1.f/768.f) + 1e-5f);
  u16* orow = out + (size_t)row * DIM;
  #pragma unroll
  for (int j = 0; j < 12; ++j){
    int c = j*64 + lane;
    orow[c] = f2bf((v[j]-mu)*rs*g[c] + bb[c]);
  }
}

// ---------- GEMM: A[M=2048][K] bf16 row-major, BT[N][K] bf16, 128x128 tile, BK=32 ----------
// 1-D grid, bijective XCD swizzle + m-fastest grouping (16 m-tiles share one B-panel per XCD).
// LDS tile [128][32] with XOR chunk-swizzle: slot s of row r holds global k-chunk s^((r>>1)&3).
// Source side pre-swizzles within the 64B line (coalescing preserved, rule #21 both-sides).
// EPI: 0 = fp32 store (no bias); 1 = +bias -> bf16; 2 = +bias, gelu -> bf16; 3 = +bias, += fp32 resid
template<int EPI>
__global__ __launch_bounds__(256) void k_gemm(const u16* __restrict__ A, const u16* __restrict__ BT,
                                              const float* __restrict__ bias, void* __restrict__ outp,
                                              int N, int K){
  __shared__ __align__(16) u16 Ab[2][128][32];
  __shared__ __align__(16) u16 Bb[2][128][32];
  int t = threadIdx.x, w = t >> 6, l = t & 63;
  // XCD swizzle: each XCD gets a contiguous wgid chunk; within chunk m varies fastest.
  int cpx = gridDim.x >> 3;               // all grids divisible by 8
  int wgid = (blockIdx.x & 7) * cpx + (blockIdx.x >> 3);
  int m0 = (wgid & 15) * 128;             // M/128 == 16 always (M = 2048)
  int n0 = (wgid >> 4) * 128;
  const u16* Ag = A  + (size_t)m0 * K;
  const u16* Bg = BT + (size_t)n0 * K;
  f32x4 acc[4][4] = {};
  int NT = K >> 5;
  int lr = l >> 2;                            // staging row within 16-row group
  int cs = (((l & 3) ^ ((l >> 3) & 3)) * 8);  // swizzled source chunk (within 64B line)

  auto stage = [&](int buf, int kt){
    int k0 = kt * 32 + cs;
    int rb = w * 16;
    gload_lds16(Ag + (size_t)(rb + lr) * K + k0,      &Ab[buf][rb][0]);
    gload_lds16(Ag + (size_t)(64 + rb + lr) * K + k0, &Ab[buf][64 + rb][0]);
    gload_lds16(Bg + (size_t)(rb + lr) * K + k0,      &Bb[buf][rb][0]);
    gload_lds16(Bg + (size_t)(64 + rb + lr) * K + k0, &Bb[buf][64 + rb][0]);
  };

  stage(0, 0);
  __syncthreads();
  int wm = (w >> 1) * 64, wn = (w & 1) * 64;
  int ku = l >> 4, r16 = l & 15;
  int sl = (ku ^ ((r16 >> 1) & 3)) * 8;       // swizzled read slot (per-lane constant)
  for (int kt = 0; kt < NT; ++kt){
    int buf = kt & 1;
    if (kt + 1 < NT) stage(buf ^ 1, kt + 1);
    s16x8 af[4], bfr[4];
    #pragma unroll
    for (int mi = 0; mi < 4; ++mi) af[mi]  = *(const s16x8*)&Ab[buf][wm + mi*16 + r16][sl];
    #pragma unroll
    for (int ni = 0; ni < 4; ++ni) bfr[ni] = *(const s16x8*)&Bb[buf][wn + ni*16 + r16][sl];
    #pragma unroll
    for (int mi = 0; mi < 4; ++mi)
      #pragma unroll
      for (int ni = 0; ni < 4; ++ni)
        mfma16(acc[mi][ni], af[mi], bfr[ni]);
    __syncthreads();
  }
  asm volatile("s_nop 7\ns_nop 7\ns_nop 7\ns_nop 7");   // MFMA -> VALU hazard
  int rg = l >> 4;
  #pragma unroll
  for (int mi = 0; mi < 4; ++mi){
    #pragma unroll
    for (int ni = 0; ni < 4; ++ni){
      int col = n0 + wn + ni*16 + r16;
      float bv = (EPI != 0) ? bias[col] : 0.f;
      #pragma unroll
      for (int r = 0; r < 4; ++r){
        int row = m0 + wm + mi*16 + rg*4 + r;
        float v = acc[mi][ni][r] + bv;
        size_t oi = (size_t)row * N + col;
        if (EPI == 0)      ((float*)outp)[oi] = v;
        else if (EPI == 1) ((u16*)outp)[oi] = f2bf(v);
        else if (EPI == 2){ v = 0.5f*v*(1.f + erff(v*0.70710678118f)); ((u16*)outp)[oi] = f2bf(v); }
        else { float* p = (float*)outp + oi; *p += v; }
      }
    }
  }
}

// ---------- V transpose: qkv V-slice -> VT[b][h][64 d][1024 s] bf16 ----------
__global__ __launch_bounds__(256) void k_vt(const u16* __restrict__ qkv, u16* __restrict__ vt){
  int st = blockIdx.x * 64, h = blockIdx.y, b = blockIdx.z;
  __shared__ u16 tile[64][72];
  int t = threadIdx.x;
  int r = t >> 2, cg = (t & 3) * 16;
  const u16* src = qkv + (size_t)(b*1024 + st + r) * D3 + 2*DIM + h*64 + cg;
  *(s16x8*)&tile[r][cg]   = *(const s16x8*)src;
  *(s16x8*)&tile[r][cg+8] = *(const s16x8*)(src + 8);
  __syncthreads();
  s16x8 o0, o1;
  #pragma unroll
  for (int j = 0; j < 8; ++j){ o0[j] = (short)tile[cg+j][r]; o1[j] = (short)tile[cg+8+j][r]; }
  u16* dst = vt + ((size_t)(b*12 + h)*64 + r)*1024 + st + cg;
  *(s16x8*)dst     = o0;
  *(s16x8*)(dst+8) = o1;
}

// ---------- flash attention, MFMA 16x16x32; block = 64 q rows (4 waves x 16) ----------
__global__ __launch_bounds__(256) void k_attn(const u16* __restrict__ qkv, const u16* __restrict__ vt,
                                              u16* __restrict__ y){
  int qb = blockIdx.x, h = blockIdx.y, b = blockIdx.z;
  int t = threadIdx.x, wv = t >> 6, l = t & 63;
  int q0 = qb * 64;
  __shared__ __align__(16) u16 Kt[64][72];   // [k][d], +8 pad breaks bank conflicts
  __shared__ __align__(16) u16 Vtl[64][72];  // [d][k]
  __shared__ __align__(16) u16 Pl[4][16][72];
  int colb = l & 15, rowg = (l >> 4) * 4;
  // Q fragments (registers, constant across tiles)
  const u16* qp = qkv + (size_t)(b*1024 + q0 + wv*16 + colb) * D3 + h*64 + (l>>4)*8;
  s16x8 qa0 = *(const s16x8*)qp;
  s16x8 qa1 = *(const s16x8*)(qp + 32);
  f32x4 ao[4] = {};
  float m[4]  = {-1e30f,-1e30f,-1e30f,-1e30f};
  float ls[4] = {0.f,0.f,0.f,0.f};
  const u16* kbase = qkv + (size_t)b*1024*D3 + DIM + h*64;
  const u16* vbase = vt + (size_t)(b*12 + h)*64*1024;
  int kk = t >> 2, cg = (t & 3) * 16;
  int ntiles = qb + 1;
  for (int kt = 0; kt < ntiles; ++kt){
    { // stage K tile [k][d] and V^T tile [d][k]
      const u16* ks = kbase + (size_t)(kt*64 + kk) * D3 + cg;
      *(s16x8*)&Kt[kk][cg]    = *(const s16x8*)ks;
      *(s16x8*)&Kt[kk][cg+8]  = *(const s16x8*)(ks + 8);
      const u16* vs = vbase + (size_t)kk * 1024 + kt*64 + cg;
      *(s16x8*)&Vtl[kk][cg]   = *(const s16x8*)vs;
      *(s16x8*)&Vtl[kk][cg+8] = *(const s16x8*)(vs + 8);
    }
    __syncthreads();
    // QK^T
    f32x4 as[4];
    #pragma unroll
    for (int nf = 0; nf < 4; ++nf){
      as[nf] = 0.f;
      s16x8 b0 = *(const s16x8*)&Kt[nf*16 + colb][(l>>4)*8];
      s16x8 b1 = *(const s16x8*)&Kt[nf*16 + colb][32 + (l>>4)*8];
      mfma16(as[nf], qa0, b0);
      mfma16(as[nf], qa1, b1);
    }
    asm volatile("s_nop 7\ns_nop 7\ns_nop 7");   // MFMA -> VALU hazard
    // mask + online softmax (fp32)
    float sv[4][4];
    int qgb = q0 + wv*16 + rowg;
    #pragma unroll
    for (int nf = 0; nf < 4; ++nf){
      int kglob = kt*64 + nf*16 + colb;
      #pragma unroll
      for (int r = 0; r < 4; ++r){
        float s = as[nf][r] * 0.125f;
        sv[nf][r] = (kglob > qgb + r) ? -1e30f : s;
      }
    }
    float corr[4], rs[4];
    #pragma unroll
    for (int r = 0; r < 4; ++r){
      float v = fmaxf(fmaxf(sv[0][r], sv[1][r]), fmaxf(sv[2][r], sv[3][r]));
      v = fmaxf(v, __shfl_xor(v, 1)); v = fmaxf(v, __shfl_xor(v, 2));
      v = fmaxf(v, __shfl_xor(v, 4)); v = fmaxf(v, __shfl_xor(v, 8));
      float mn = fmaxf(m[r], v);
      corr[r] = __expf(m[r] - mn);
      m[r] = mn;
      rs[r] = 0.f;
    }
    #pragma unroll
    for (int nf = 0; nf < 4; ++nf){
      #pragma unroll
      for (int r = 0; r < 4; ++r){
        float p = __expf(sv[nf][r] - m[r]);
        rs[r] += p;
        Pl[wv][rowg + r][nf*16 + colb] = f2bf(p);
      }
    }
    #pragma unroll
    for (int r = 0; r < 4; ++r){
      float v = rs[r];
      v += __shfl_xor(v, 1); v += __shfl_xor(v, 2); v += __shfl_xor(v, 4); v += __shfl_xor(v, 8);
      ls[r] = ls[r]*corr[r] + v;
    }
    #pragma unroll
    for (int nf = 0; nf < 4; ++nf)
      #pragma unroll
      for (int r = 0; r < 4; ++r)
        ao[nf][r] *= corr[r];
    asm volatile("s_waitcnt lgkmcnt(0)" ::: "memory");   // P writes -> P reads (wave-local)
    // PV
    s16x8 pa0 = *(const s16x8*)&Pl[wv][colb][(l>>4)*8];
    s16x8 pa1 = *(const s16x8*)&Pl[wv][colb][32 + (l>>4)*8];
    #pragma unroll
    for (int nf = 0; nf < 4; ++nf){
      s16x8 v0 = *(const s16x8*)&Vtl[nf*16 + colb][(l>>4)*8];
      s16x8 v1 = *(const s16x8*)&Vtl[nf*16 + colb][32 + (l>>4)*8];
      mfma16(ao[nf], pa0, v0);
      mfma16(ao[nf], pa1, v1);
    }
    __syncthreads();
  }
  asm volatile("s_nop 7\ns_nop 7\ns_nop 7\ns_nop 7");
  #pragma unroll
  for (int nf = 0; nf < 4; ++nf){
    #pragma unroll
    for (int r = 0; r < 4; ++r){
      int qg = q0 + wv*16 + rowg + r;
      int d  = nf*16 + colb;
      y[(size_t)(b*1024 + qg)*DIM + h*64 + d] = f2bf(ao[nf][r] / ls[r]);
    }
  }
}

extern "C" void kernel_launch(void* const* d_in, const int* in_sizes, int n_in,
                              void* d_out, int out_size, void* d_ws, size_t ws_size,
                              hipStream_t stream){
  (void)in_sizes; (void)n_in; (void)out_size; (void)ws_size;
  const int*   idx     = (const int*)  d_in[0];
  const float* tok_emb = (const float*)d_in[1];
  const float* pos_emb = (const float*)d_in[2];
  const float* ln1_g   = (const float*)d_in[3];
  const float* ln1_b   = (const float*)d_in[4];
  const float* qkv_w   = (const float*)d_in[5];
  const float* qkv_b   = (const float*)d_in[6];
  const float* attn_w  = (const float*)d_in[7];
  const float* attn_b  = (const float*)d_in[8];
  const float* ln2_g   = (const float*)d_in[9];
  const float* ln2_b   = (const float*)d_in[10];
  const float* fc_w    = (const float*)d_in[11];
  const float* fc_b    = (const float*)d_in[12];
  const float* mlp_w   = (const float*)d_in[13];
  const float* mlp_b   = (const float*)d_in[14];
  const float* lnf_g   = (const float*)d_in[15];
  const float* lnf_b   = (const float*)d_in[16];

  char* ws = (char*)d_ws;
  size_t off = 0;
  auto take = [&](size_t bytes)->char*{
    char* p = ws + off; off += (bytes + 255) & ~(size_t)255; return p;
  };
  u16*   wqkvT = (u16*)  take((size_t)LAYERS*D3*DIM*2);
  u16*   wattT = (u16*)  take((size_t)LAYERS*DIM*DIM*2);
  u16*   wfcT  = (u16*)  take((size_t)LAYERS*DF*DIM*2);
  u16*   wmlpT = (u16*)  take((size_t)LAYERS*DIM*DF*2);
  u16*   embB  = (u16*)  take((size_t)VOCAB*DIM*2);
  float* x     = (float*)take((size_t)TT*DIM*4);
  u16*   hbuf  = (u16*)  take((size_t)TT*DIM*2);
  u16*   qkvb  = (u16*)  take((size_t)TT*D3*2);
  u16*   yb    = (u16*)  take((size_t)TT*DIM*2);
  u16*   fcb   = (u16*)  take((size_t)TT*DF*2);
  u16*   xfb   = (u16*)  take((size_t)TT*DIM*2);
  u16*   vtb   = (u16*)  take((size_t)2*12*64*1024*2);

  // weight prep (bf16 + B^T layout)
  k_transpose<<<dim3(D3/32,  DIM/32, LAYERS), 256, 0, stream>>>(qkv_w, wqkvT, DIM, D3);
  k_transpose<<<dim3(DIM/32, DIM/32, LAYERS), 256, 0, stream>>>(attn_w, wattT, DIM, DIM);
  k_transpose<<<dim3(DF/32,  DIM/32, LAYERS), 256, 0, stream>>>(fc_w,  wfcT,  DIM, DF);
  k_transpose<<<dim3(DIM/32, DF/32,  LAYERS), 256, 0, stream>>>(mlp_w, wmlpT, DF, DIM);
  k_convert<<<(VOCAB*DIM)/1024, 256, 0, stream>>>(tok_emb, embB);

  k_embed<<<TT, 256, 0, stream>>>(idx, tok_emb, pos_emb, x);

  for (int l = 0; l < LAYERS; ++l){
    k_ln<<<TT/4, 256, 0, stream>>>(x, ln1_g + l*DIM, ln1_b + l*DIM, hbuf);
    k_gemm<1><<<dim3((TT/128)*(D3/128)), 256, 0, stream>>>(
        hbuf, wqkvT + (size_t)l*D3*DIM, qkv_b + l*D3, qkvb, D3, DIM);
    k_vt<<<dim3(16, 12, 2), 256, 0, stream>>>(qkvb, vtb);
    k_attn<<<dim3(16, 12, 2), 256, 0, stream>>>(qkvb, vtb, yb);
    k_gemm<3><<<dim3((TT/128)*(DIM/128)), 256, 0, stream>>>(
        yb, wattT + (size_t)l*DIM*DIM, attn_b + l*DIM, x, DIM, DIM);
    k_ln<<<TT/4, 256, 0, stream>>>(x, ln2_g + l*DIM, ln2_b + l*DIM, hbuf);
    k_gemm<2><<<dim3((TT/128)*(DF/128)), 256, 0, stream>>>(
        hbuf, wfcT + (size_t)l*DF*DIM, fc_b + l*DF, fcb, DF, DIM);
    k_gemm<3><<<dim3((TT/128)*(DIM/128)), 256, 0, stream>>>(
        fcb, wmlpT + (size_t)l*DIM*DF, mlp_b + l*DIM, x, DIM, DF);
  }
  k_ln<<<TT/4, 256, 0, stream>>>(x, lnf_g, lnf_b, xfb);
  k_gemm<0><<<dim3((TT/128)*(VOCAB/128)), 256, 0, stream>>>(
      xfb, embB, nullptr, d_out, VOCAB, DIM);
}

// Round 4
// 1380.071 us; speedup vs baseline: 1.3826x; 1.1215x over previous
//
#include <hip/hip_runtime.h>

#define LAYERS 6
#define DIM    768
#define D3     2304
#define DF     3072
#define TT     2048
#define VOCAB  32000

typedef unsigned short u16;
typedef __attribute__((ext_vector_type(4))) float f32x4;
typedef __attribute__((ext_vector_type(8))) short s16x8;
typedef __attribute__((ext_vector_type(4))) unsigned short u16x4;

__device__ __forceinline__ float bf2f(u16 a){
  unsigned int u = ((unsigned int)a) << 16;
  float f; __builtin_memcpy(&f, &u, 4); return f;
}
__device__ __forceinline__ u16 f2bf(float f){
  unsigned int u; __builtin_memcpy(&u, &f, 4);
  u = (u + 0x7fffu + ((u >> 16) & 1u)) >> 16;
  return (u16)u;
}
__device__ __forceinline__ void gload_lds16(const void* g, void* l){
  __builtin_amdgcn_global_load_lds(
      (const __attribute__((address_space(1))) unsigned int*)g,
      (__attribute__((address_space(3))) unsigned int*)l, 16, 0, 0);
}
__device__ __forceinline__ void mfma16(f32x4& d, s16x8 a, s16x8 b){
  asm("v_mfma_f32_16x16x32_bf16 %0, %1, %2, %0" : "+v"(d) : "v"(a), "v"(b));
}

// ---------- weight fp32 [R][C] -> bf16 [C][R] (B^T layout), 64x64 tiles, grid.z = layer ----------
__global__ __launch_bounds__(256) void k_transpose(const float* __restrict__ in,
                                                   u16* __restrict__ out, int R, int C){
  __shared__ float tile[64][65];
  size_t ls = (size_t)R * C;
  in  += ls * blockIdx.z;
  out += ls * blockIdx.z;
  int r0 = blockIdx.y * 64, c0 = blockIdx.x * 64;
  int t = threadIdx.x;
  int tr = t >> 4, tc = (t & 15) * 4;
  #pragma unroll
  for (int j = 0; j < 4; ++j){
    float4 v = *(const float4*)(in + (size_t)(r0 + tr + j*16) * C + c0 + tc);
    tile[tr + j*16][tc+0] = v.x; tile[tr + j*16][tc+1] = v.y;
    tile[tr + j*16][tc+2] = v.z; tile[tr + j*16][tc+3] = v.w;
  }
  __syncthreads();
  #pragma unroll
  for (int j = 0; j < 4; ++j){
    u16x4 o;
    #pragma unroll
    for (int i = 0; i < 4; ++i) o[i] = f2bf(tile[tc+i][tr + j*16]);
    *(u16x4*)(out + (size_t)(c0 + tr + j*16) * R + r0 + tc) = o;
  }
}

// ---------- fp32 -> bf16 elementwise (tok_emb for tied lm_head) ----------
__global__ __launch_bounds__(256) void k_convert(const float* __restrict__ in, u16* __restrict__ out){
  int i = blockIdx.x * 256 + threadIdx.x;
  float4 v = ((const float4*)in)[i];
  u16x4 o;
  o[0] = f2bf(v.x); o[1] = f2bf(v.y); o[2] = f2bf(v.z); o[3] = f2bf(v.w);
  ((u16x4*)out)[i] = o;
}

// ---------- token + positional embedding -> x fp32 ----------
__global__ __launch_bounds__(256) void k_embed(const int* __restrict__ idx, const float* __restrict__ te,
                                               const float* __restrict__ pe, float* __restrict__ x){
  int t = blockIdx.x;
  int id = idx[t];
  const float* a = te + (size_t)id * DIM;
  const float* p = pe + (size_t)(t & 1023) * DIM;
  float* o = x + (size_t)t * DIM;
  #pragma unroll
  for (int j = 0; j < 3; ++j){
    int d = j * 256 + threadIdx.x;
    o[d] = a[d] + p[d];
  }
}

// ---------- layernorm fp32 -> bf16, one wave per row ----------
__global__ __launch_bounds__(256) void k_ln(const float* __restrict__ x, const float* __restrict__ g,
                                            const float* __restrict__ bb, u16* __restrict__ out){
  int row = blockIdx.x * 4 + (threadIdx.x >> 6);
  int lane = threadIdx.x & 63;
  const float* xr = x + (size_t)row * DIM;
  float v[12], s = 0.f;
  #pragma unroll
  for (int j = 0; j < 12; ++j){ v[j] = xr[j*64 + lane]; s += v[j]; }
  #pragma unroll
  for (int o = 32; o; o >>= 1) s += __shfl_xor(s, o);
  float mu = s * (1.f/768.f);
  float vs = 0.f;
  #pragma unroll
  for (int j = 0; j < 12; ++j){ float d = v[j]-mu; vs += d*d; }
  #pragma unroll
  for (int o = 32; o; o >>= 1) vs += __shfl_xor(vs, o);
  float rs = rsqrtf(vs * (1.f/768.f) + 1e-5f);
  u16* orow = out + (size_t)row * DIM;
  #pragma unroll
  for (int j = 0; j < 12; ++j){
    int c = j*64 + lane;
    orow[c] = f2bf((v[j]-mu)*rs*g[c] + bb[c]);
  }
}

// ---------- GEMM: A[M=2048][K] bf16 row-major, BT[N][K] bf16, TMx128 tile, BK=32 ----------
// TM = 128 (wave tile 64x64) or 64 (wave tile 32x64, for small-N GEMMs -> 2x grid).
// TAG distinguishes call sites in rocprof. XCD swizzle + m-fastest grouping; XOR chunk-swizzle LDS.
// EPI: 0 = fp32 store (no bias); 1 = +bias -> bf16; 2 = +bias, gelu -> bf16; 3 = +bias, += fp32 resid
template<int EPI, int TM, int TAG>
__global__ __launch_bounds__(256) void k_gemm(const u16* __restrict__ A, const u16* __restrict__ BT,
                                              const float* __restrict__ bias, void* __restrict__ outp,
                                              int N, int K){
  constexpr int MI  = TM / 32;       // m-fragments per wave
  constexpr int MBC = TT / TM;       // m-blocks per n-panel
  __shared__ __align__(16) u16 Ab[2][TM][32];
  __shared__ __align__(16) u16 Bb[2][128][32];
  int t = threadIdx.x, w = t >> 6, l = t & 63;
  // XCD swizzle: each XCD gets a contiguous wgid chunk; within chunk m varies fastest.
  int cpx = gridDim.x >> 3;               // all grids divisible by 8
  int wgid = (blockIdx.x & 7) * cpx + (blockIdx.x >> 3);
  int m0 = (wgid & (MBC - 1)) * TM;
  int n0 = (wgid / MBC) * 128;
  const u16* Ag = A  + (size_t)m0 * K;
  const u16* Bg = BT + (size_t)n0 * K;
  f32x4 acc[MI][4] = {};
  int NT = K >> 5;
  int lr = l >> 2;                            // staging row within 16-row group
  int cs = (((l & 3) ^ ((l >> 3) & 3)) * 8);  // swizzled source chunk (within 64B line)

  auto stage = [&](int buf, int kt){
    int k0 = kt * 32 + cs;
    int rb = w * 16;
    gload_lds16(Ag + (size_t)(rb + lr) * K + k0,      &Ab[buf][rb][0]);
    if constexpr (TM == 128)
      gload_lds16(Ag + (size_t)(64 + rb + lr) * K + k0, &Ab[buf][64 + rb][0]);
    gload_lds16(Bg + (size_t)(rb + lr) * K + k0,      &Bb[buf][rb][0]);
    gload_lds16(Bg + (size_t)(64 + rb + lr) * K + k0, &Bb[buf][64 + rb][0]);
  };

  stage(0, 0);
  __syncthreads();
  int wm = (w >> 1) * (TM / 2), wn = (w & 1) * 64;
  int ku = l >> 4, r16 = l & 15;
  int sl = (ku ^ ((r16 >> 1) & 3)) * 8;       // swizzled read slot (per-lane constant)
  for (int kt = 0; kt < NT; ++kt){
    int buf = kt & 1;
    if (kt + 1 < NT) stage(buf ^ 1, kt + 1);
    s16x8 af[MI], bfr[4];
    #pragma unroll
    for (int mi = 0; mi < MI; ++mi) af[mi]  = *(const s16x8*)&Ab[buf][wm + mi*16 + r16][sl];
    #pragma unroll
    for (int ni = 0; ni < 4; ++ni)  bfr[ni] = *(const s16x8*)&Bb[buf][wn + ni*16 + r16][sl];
    #pragma unroll
    for (int mi = 0; mi < MI; ++mi)
      #pragma unroll
      for (int ni = 0; ni < 4; ++ni)
        mfma16(acc[mi][ni], af[mi], bfr[ni]);
    __syncthreads();
  }
  asm volatile("s_nop 7\ns_nop 7\ns_nop 7\ns_nop 7");   // MFMA -> VALU hazard
  int rg = l >> 4;
  #pragma unroll
  for (int mi = 0; mi < MI; ++mi){
    #pragma unroll
    for (int ni = 0; ni < 4; ++ni){
      int col = n0 + wn + ni*16 + r16;
      float bv = (EPI != 0) ? bias[col] : 0.f;
      #pragma unroll
      for (int r = 0; r < 4; ++r){
        int row = m0 + wm + mi*16 + rg*4 + r;
        float v = acc[mi][ni][r] + bv;
        size_t oi = (size_t)row * N + col;
        if (EPI == 0)      ((float*)outp)[oi] = v;
        else if (EPI == 1) ((u16*)outp)[oi] = f2bf(v);
        else if (EPI == 2){ v = 0.5f*v*(1.f + erff(v*0.70710678118f)); ((u16*)outp)[oi] = f2bf(v); }
        else { float* p = (float*)outp + oi; *p += v; }
      }
    }
  }
}

// ---------- V transpose: qkv V-slice -> VT[b][h][64 d][1024 s] bf16 ----------
__global__ __launch_bounds__(256) void k_vt(const u16* __restrict__ qkv, u16* __restrict__ vt){
  int st = blockIdx.x * 64, h = blockIdx.y, b = blockIdx.z;
  __shared__ u16 tile[64][72];
  int t = threadIdx.x;
  int r = t >> 2, cg = (t & 3) * 16;
  const u16* src = qkv + (size_t)(b*1024 + st + r) * D3 + 2*DIM + h*64 + cg;
  *(s16x8*)&tile[r][cg]   = *(const s16x8*)src;
  *(s16x8*)&tile[r][cg+8] = *(const s16x8*)(src + 8);
  __syncthreads();
  s16x8 o0, o1;
  #pragma unroll
  for (int j = 0; j < 8; ++j){ o0[j] = (short)tile[cg+j][r]; o1[j] = (short)tile[cg+8+j][r]; }
  u16* dst = vt + ((size_t)(b*12 + h)*64 + r)*1024 + st + cg;
  *(s16x8*)dst     = o0;
  *(s16x8*)(dst+8) = o1;
}

// ---------- flash attention, MFMA 16x16x32; block = 64 q rows (4 waves x 16) ----------
__global__ __launch_bounds__(256) void k_attn(const u16* __restrict__ qkv, const u16* __restrict__ vt,
                                              u16* __restrict__ y){
  int qb = blockIdx.x, h = blockIdx.y, b = blockIdx.z;
  int t = threadIdx.x, wv = t >> 6, l = t & 63;
  int q0 = qb * 64;
  __shared__ __align__(16) u16 Kt[64][72];   // [k][d], +8 pad breaks bank conflicts
  __shared__ __align__(16) u16 Vtl[64][72];  // [d][k]
  __shared__ __align__(16) u16 Pl[4][16][72];
  int colb = l & 15, rowg = (l >> 4) * 4;
  // Q fragments (registers, constant across tiles)
  const u16* qp = qkv + (size_t)(b*1024 + q0 + wv*16 + colb) * D3 + h*64 + (l>>4)*8;
  s16x8 qa0 = *(const s16x8*)qp;
  s16x8 qa1 = *(const s16x8*)(qp + 32);
  f32x4 ao[4] = {};
  float m[4]  = {-1e30f,-1e30f,-1e30f,-1e30f};
  float ls[4] = {0.f,0.f,0.f,0.f};
  const u16* kbase = qkv + (size_t)b*1024*D3 + DIM + h*64;
  const u16* vbase = vt + (size_t)(b*12 + h)*64*1024;
  int kk = t >> 2, cg = (t & 3) * 16;
  int ntiles = qb + 1;
  for (int kt = 0; kt < ntiles; ++kt){
    { // stage K tile [k][d] and V^T tile [d][k]
      const u16* ks = kbase + (size_t)(kt*64 + kk) * D3 + cg;
      *(s16x8*)&Kt[kk][cg]    = *(const s16x8*)ks;
      *(s16x8*)&Kt[kk][cg+8]  = *(const s16x8*)(ks + 8);
      const u16* vs = vbase + (size_t)kk * 1024 + kt*64 + cg;
      *(s16x8*)&Vtl[kk][cg]   = *(const s16x8*)vs;
      *(s16x8*)&Vtl[kk][cg+8] = *(const s16x8*)(vs + 8);
    }
    __syncthreads();
    // QK^T
    f32x4 as[4];
    #pragma unroll
    for (int nf = 0; nf < 4; ++nf){
      as[nf] = 0.f;
      s16x8 b0 = *(const s16x8*)&Kt[nf*16 + colb][(l>>4)*8];
      s16x8 b1 = *(const s16x8*)&Kt[nf*16 + colb][32 + (l>>4)*8];
      mfma16(as[nf], qa0, b0);
      mfma16(as[nf], qa1, b1);
    }
    asm volatile("s_nop 7\ns_nop 7\ns_nop 7");   // MFMA -> VALU hazard
    // mask + online softmax (fp32)
    float sv[4][4];
    int qgb = q0 + wv*16 + rowg;
    #pragma unroll
    for (int nf = 0; nf < 4; ++nf){
      int kglob = kt*64 + nf*16 + colb;
      #pragma unroll
      for (int r = 0; r < 4; ++r){
        float s = as[nf][r] * 0.125f;
        sv[nf][r] = (kglob > qgb + r) ? -1e30f : s;
      }
    }
    float corr[4], rs[4];
    #pragma unroll
    for (int r = 0; r < 4; ++r){
      float v = fmaxf(fmaxf(sv[0][r], sv[1][r]), fmaxf(sv[2][r], sv[3][r]));
      v = fmaxf(v, __shfl_xor(v, 1)); v = fmaxf(v, __shfl_xor(v, 2));
      v = fmaxf(v, __shfl_xor(v, 4)); v = fmaxf(v, __shfl_xor(v, 8));
      float mn = fmaxf(m[r], v);
      corr[r] = __expf(m[r] - mn);
      m[r] = mn;
      rs[r] = 0.f;
    }
    #pragma unroll
    for (int nf = 0; nf < 4; ++nf){
      #pragma unroll
      for (int r = 0; r < 4; ++r){
        float p = __expf(sv[nf][r] - m[r]);
        rs[r] += p;
        Pl[wv][rowg + r][nf*16 + colb] = f2bf(p);
      }
    }
    #pragma unroll
    for (int r = 0; r < 4; ++r){
      float v = rs[r];
      v += __shfl_xor(v, 1); v += __shfl_xor(v, 2); v += __shfl_xor(v, 4); v += __shfl_xor(v, 8);
      ls[r] = ls[r]*corr[r] + v;
    }
    #pragma unroll
    for (int nf = 0; nf < 4; ++nf)
      #pragma unroll
      for (int r = 0; r < 4; ++r)
        ao[nf][r] *= corr[r];
    asm volatile("s_waitcnt lgkmcnt(0)" ::: "memory");   // P writes -> P reads (wave-local)
    // PV
    s16x8 pa0 = *(const s16x8*)&Pl[wv][colb][(l>>4)*8];
    s16x8 pa1 = *(const s16x8*)&Pl[wv][colb][32 + (l>>4)*8];
    #pragma unroll
    for (int nf = 0; nf < 4; ++nf){
      s16x8 v0 = *(const s16x8*)&Vtl[nf*16 + colb][(l>>4)*8];
      s16x8 v1 = *(const s16x8*)&Vtl[nf*16 + colb][32 + (l>>4)*8];
      mfma16(ao[nf], pa0, v0);
      mfma16(ao[nf], pa1, v1);
    }
    __syncthreads();
  }
  asm volatile("s_nop 7\ns_nop 7\ns_nop 7\ns_nop 7");
  #pragma unroll
  for (int nf = 0; nf < 4; ++nf){
    #pragma unroll
    for (int r = 0; r < 4; ++r){
      int qg = q0 + wv*16 + rowg + r;
      int d  = nf*16 + colb;
      y[(size_t)(b*1024 + qg)*DIM + h*64 + d] = f2bf(ao[nf][r] / ls[r]);
    }
  }
}

extern "C" void kernel_launch(void* const* d_in, const int* in_sizes, int n_in,
                              void* d_out, int out_size, void* d_ws, size_t ws_size,
                              hipStream_t stream){
  (void)in_sizes; (void)n_in; (void)out_size; (void)ws_size;
  const int*   idx     = (const int*)  d_in[0];
  const float* tok_emb = (const float*)d_in[1];
  const float* pos_emb = (const float*)d_in[2];
  const float* ln1_g   = (const float*)d_in[3];
  const float* ln1_b   = (const float*)d_in[4];
  const float* qkv_w   = (const float*)d_in[5];
  const float* qkv_b   = (const float*)d_in[6];
  const float* attn_w  = (const float*)d_in[7];
  const float* attn_b  = (const float*)d_in[8];
  const float* ln2_g   = (const float*)d_in[9];
  const float* ln2_b   = (const float*)d_in[10];
  const float* fc_w    = (const float*)d_in[11];
  const float* fc_b    = (const float*)d_in[12];
  const float* mlp_w   = (const float*)d_in[13];
  const float* mlp_b   = (const float*)d_in[14];
  const float* lnf_g   = (const float*)d_in[15];
  const float* lnf_b   = (const float*)d_in[16];

  char* ws = (char*)d_ws;
  size_t off = 0;
  auto take = [&](size_t bytes)->char*{
    char* p = ws + off; off += (bytes + 255) & ~(size_t)255; return p;
  };
  u16*   wqkvT = (u16*)  take((size_t)LAYERS*D3*DIM*2);
  u16*   wattT = (u16*)  take((size_t)LAYERS*DIM*DIM*2);
  u16*   wfcT  = (u16*)  take((size_t)LAYERS*DF*DIM*2);
  u16*   wmlpT = (u16*)  take((size_t)LAYERS*DIM*DF*2);
  u16*   embB  = (u16*)  take((size_t)VOCAB*DIM*2);
  float* x     = (float*)take((size_t)TT*DIM*4);
  u16*   hbuf  = (u16*)  take((size_t)TT*DIM*2);
  u16*   qkvb  = (u16*)  take((size_t)TT*D3*2);
  u16*   yb    = (u16*)  take((size_t)TT*DIM*2);
  u16*   fcb   = (u16*)  take((size_t)TT*DF*2);
  u16*   xfb   = (u16*)  take((size_t)TT*DIM*2);
  u16*   vtb   = (u16*)  take((size_t)2*12*64*1024*2);

  // weight prep (bf16 + B^T layout)
  k_transpose<<<dim3(D3/64,  DIM/64, LAYERS), 256, 0, stream>>>(qkv_w, wqkvT, DIM, D3);
  k_transpose<<<dim3(DIM/64, DIM/64, LAYERS), 256, 0, stream>>>(attn_w, wattT, DIM, DIM);
  k_transpose<<<dim3(DF/64,  DIM/64, LAYERS), 256, 0, stream>>>(fc_w,  wfcT,  DIM, DF);
  k_transpose<<<dim3(DIM/64, DF/64,  LAYERS), 256, 0, stream>>>(mlp_w, wmlpT, DF, DIM);
  k_convert<<<(VOCAB*DIM)/1024, 256, 0, stream>>>(tok_emb, embB);

  k_embed<<<TT, 256, 0, stream>>>(idx, tok_emb, pos_emb, x);

  for (int l = 0; l < LAYERS; ++l){
    k_ln<<<TT/4, 256, 0, stream>>>(x, ln1_g + l*DIM, ln1_b + l*DIM, hbuf);
    k_gemm<1,128,0><<<dim3((TT/128)*(D3/128)), 256, 0, stream>>>(
        hbuf, wqkvT + (size_t)l*D3*DIM, qkv_b + l*D3, qkvb, D3, DIM);
    k_vt<<<dim3(16, 12, 2), 256, 0, stream>>>(qkvb, vtb);
    k_attn<<<dim3(16, 12, 2), 256, 0, stream>>>(qkvb, vtb, yb);
    k_gemm<3,64,1><<<dim3((TT/64)*(DIM/128)), 256, 0, stream>>>(
        yb, wattT + (size_t)l*DIM*DIM, attn_b + l*DIM, x, DIM, DIM);
    k_ln<<<TT/4, 256, 0, stream>>>(x, ln2_g + l*DIM, ln2_b + l*DIM, hbuf);
    k_gemm<2,128,2><<<dim3((TT/128)*(DF/128)), 256, 0, stream>>>(
        hbuf, wfcT + (size_t)l*DF*DIM, fc_b + l*DF, fcb, DF, DIM);
    k_gemm<3,64,3><<<dim3((TT/64)*(DIM/128)), 256, 0, stream>>>(
        fcb, wmlpT + (size_t)l*DIM*DF, mlp_b + l*DIM, x, DIM, DF);
  }
  k_ln<<<TT/4, 256, 0, stream>>>(x, lnf_g, lnf_b, xfb);
  k_gemm<0,128,4><<<dim3((TT/128)*(VOCAB/128)), 256, 0, stream>>>(
      xfb, embB, nullptr, d_out, VOCAB, DIM);
}